// Round 1
// baseline (403.056 us; speedup 1.0000x reference)
//
#include <hip/hip_runtime.h>
#include <hip/hip_bf16.h>
#include <math.h>

#define B 4
#define L 2048
#define H 8
#define D 64
#define SK 40
#define U 40

// ws layout (bytes)
#define OFF_M    0           // B*H*L floats = 262144 B
#define OFF_TOP  262144      // B*H*U ints  = 5120 B
#define OFF_T    270336      // B*H*U*L floats = 10485760 B
#define OFF_PART 10756096    // 8 * B*H*U*D floats = 2621440 B

__device__ __forceinline__ float dot4(float4 a, float4 b) {
    return fmaf(a.x, b.x, fmaf(a.y, b.y, fmaf(a.z, b.z, a.w * b.w)));
}

// K1: M[b,h,q] = max_s dot(Q[bhq], K[bh,idx[q,s]]) - (1/L) * sum_s dot(...)
// one wave per query; lane = sample (lanes >= SK masked out of the reduction)
__global__ __launch_bounds__(256) void k_msamp(const float* __restrict__ Q,
                                               const float* __restrict__ K,
                                               const int* __restrict__ idx,
                                               float* __restrict__ M) {
    int gid  = blockIdx.x * 256 + threadIdx.x;
    int wid  = gid >> 6;                 // [0, B*H*L)
    int lane = threadIdx.x & 63;
    int q  = wid & (L - 1);
    int bh = wid >> 11;                  // b*H + h
    int h  = bh & (H - 1);
    int b  = bh >> 3;

    int s = lane;
    int ksel = (s < SK) ? idx[q * SK + s] : idx[q * SK];

    const float4* qrow = (const float4*)(Q + (size_t)((b * L + q) * H + h) * D);
    const float4* krow = (const float4*)(K + (size_t)((b * L + ksel) * H + h) * D);

    float dot = 0.f;
#pragma unroll
    for (int i = 0; i < 16; ++i) {
        float4 kv = krow[i];
        float4 qv = qrow[i];   // wave-uniform address -> scalar-load friendly
        dot += dot4(qv, kv);
    }

    float vmax = (s < SK) ? dot : -__builtin_inff();
    float vsum = (s < SK) ? dot : 0.f;
#pragma unroll
    for (int o = 32; o; o >>= 1) {
        vmax = fmaxf(vmax, __shfl_xor(vmax, o, 64));
        vsum += __shfl_xor(vsum, o, 64);
    }
    if (lane == 0) M[wid] = vmax - vsum * (1.0f / (float)L);
}

// K2: top-U argmax per (b,h), descending, ties -> lowest index (matches lax.top_k)
__global__ __launch_bounds__(64) void k_topk(const float* __restrict__ M,
                                             int* __restrict__ top) {
    __shared__ float v[L];
    int bh = blockIdx.x;
    int lane = threadIdx.x;
    const float* m = M + (size_t)bh * L;
    for (int i = lane; i < L; i += 64) v[i] = m[i];
    __syncthreads();
    for (int it = 0; it < U; ++it) {
        float best = -__builtin_inff();
        int bi = 0x7fffffff;
        for (int i = lane; i < L; i += 64) {
            float val = v[i];
            if (val > best) { best = val; bi = i; }   // ascending i: lowest idx wins ties
        }
#pragma unroll
        for (int o = 32; o; o >>= 1) {
            float ob = __shfl_xor(best, o, 64);
            int   oi = __shfl_xor(bi, o, 64);
            if (ob > best || (ob == best && oi < bi)) { best = ob; bi = oi; }
        }
        if (lane == 0) { top[bh * U + it] = bi; v[bi] = -__builtin_inff(); }
        __syncthreads();
    }
}

// K3a: scores[bh,u,k] = 0.125 * dot(Q[bh, top[bh,u]], K[bh,k])
// thread-per-k, K row in registers, uniform Q loads
__global__ __launch_bounds__(256) void k_scores(const float* __restrict__ Q,
                                                const float* __restrict__ K,
                                                const int* __restrict__ top,
                                                float* __restrict__ T) {
    int bh = blockIdx.x >> 3;
    int kc = blockIdx.x & 7;
    int h = bh & (H - 1), b = bh >> 3;
    int k = kc * 256 + threadIdx.x;

    const float4* krow = (const float4*)(K + (size_t)((b * L + k) * H + h) * D);
    float4 kv[16];
#pragma unroll
    for (int i = 0; i < 16; ++i) kv[i] = krow[i];

    float* Trow = T + (size_t)bh * U * L + k;
    for (int u = 0; u < U; ++u) {
        int qidx = top[bh * U + u];  // uniform
        const float4* qrow = (const float4*)(Q + (size_t)((b * L + qidx) * H + h) * D);
        float s = 0.f;
#pragma unroll
        for (int i = 0; i < 16; ++i) s += dot4(qrow[i], kv[i]);
        Trow[(size_t)u * L] = s * 0.125f;
    }
}

// K3b: per row (bh,u): softmax over k then suffix-sum -> T[u,j] = sum_{k>=j} attn[k]
__global__ __launch_bounds__(256) void k_softsuf(float* __restrict__ T) {
    __shared__ float red[256];
    __shared__ float arr[256];
    int row = blockIdx.x;                  // [0, B*H*U)
    float* t = T + (size_t)row * L;
    int tid = threadIdx.x;

    const float4* p = (const float4*)(t + tid * 8);
    float4 a = p[0], c = p[1];
    float x[8] = {a.x, a.y, a.z, a.w, c.x, c.y, c.z, c.w};

    float mx = x[0];
#pragma unroll
    for (int i = 1; i < 8; ++i) mx = fmaxf(mx, x[i]);
    red[tid] = mx;
    __syncthreads();
    for (int s = 128; s; s >>= 1) {
        if (tid < s) red[tid] = fmaxf(red[tid], red[tid + s]);
        __syncthreads();
    }
    float maxv = red[0];
    __syncthreads();

    float e[8];
#pragma unroll
    for (int i = 0; i < 8; ++i) e[i] = __expf(x[i] - maxv);
    // local suffix sums
    float ls[8];
    ls[7] = e[7];
#pragma unroll
    for (int i = 6; i >= 0; --i) ls[i] = e[i] + ls[i + 1];
    float mytotal = ls[0];

    arr[tid] = mytotal;
    __syncthreads();
    for (int s = 1; s < 256; s <<= 1) {
        float add = (tid + s < 256) ? arr[tid + s] : 0.f;
        __syncthreads();
        arr[tid] += add;
        __syncthreads();
    }
    float denom = arr[0];
    float off = arr[tid] - mytotal;
    float r = 1.0f / denom;

    float4 o0 = make_float4((ls[0] + off) * r, (ls[1] + off) * r,
                            (ls[2] + off) * r, (ls[3] + off) * r);
    float4 o1 = make_float4((ls[4] + off) * r, (ls[5] + off) * r,
                            (ls[6] + off) * r, (ls[7] + off) * r);
    float4* po = (float4*)(t + tid * 8);
    po[0] = o0; po[1] = o1;
}

// K3c: partial context: part[jc,bh,u,d] = sum_{j in chunk} T[bh,u,j] * V[b,j,h,d]
__global__ __launch_bounds__(256) void k_ctx(const float* __restrict__ V,
                                             const float* __restrict__ T,
                                             float* __restrict__ part) {
    __shared__ float red[4 * U * D];   // 40 KiB
    int bh = blockIdx.x >> 3;
    int jc = blockIdx.x & 7;
    int b = bh >> 3, h = bh & (H - 1);
    int d  = threadIdx.x & 63;
    int jg = threadIdx.x >> 6;         // 0..3, wave id

    float acc[U];
#pragma unroll
    for (int u = 0; u < U; ++u) acc[u] = 0.f;

    const float* Tb = T + (size_t)bh * U * L;
    for (int jj4 = 0; jj4 < 16; ++jj4) {
        int j0 = jc * 256 + jg * 64 + jj4 * 4;
        float v0 = V[(size_t)((b * L + j0 + 0) * H + h) * D + d];
        float v1 = V[(size_t)((b * L + j0 + 1) * H + h) * D + d];
        float v2 = V[(size_t)((b * L + j0 + 2) * H + h) * D + d];
        float v3 = V[(size_t)((b * L + j0 + 3) * H + h) * D + d];
#pragma unroll
        for (int u = 0; u < U; ++u) {
            float4 tv = *(const float4*)(Tb + (size_t)u * L + j0);  // wave-uniform
            acc[u] = fmaf(tv.x, v0, fmaf(tv.y, v1, fmaf(tv.z, v2, fmaf(tv.w, v3, acc[u]))));
        }
    }

#pragma unroll
    for (int u = 0; u < U; ++u) red[(jg * U + u) * D + d] = acc[u];
    __syncthreads();
    for (int i = threadIdx.x; i < U * D; i += 256) {
        float s = red[i] + red[U * D + i] + red[2 * U * D + i] + red[3 * U * D + i];
        part[(size_t)(jc * (B * H) + bh) * (U * D) + i] = s;
    }
}

// final reduce over the 8 j-chunks
__global__ __launch_bounds__(256) void k_red(const float* __restrict__ part,
                                             float* __restrict__ out) {
    int o = blockIdx.x * 256 + threadIdx.x;
    if (o >= B * H * U * D) return;
    int bh = o / (U * D);
    int rest = o - bh * (U * D);
    float s = 0.f;
#pragma unroll
    for (int jc = 0; jc < 8; ++jc)
        s += part[(size_t)(jc * (B * H) + bh) * (U * D) + rest];
    out[o] = s;
}

extern "C" void kernel_launch(void* const* d_in, const int* in_sizes, int n_in,
                              void* d_out, int out_size, void* d_ws, size_t ws_size,
                              hipStream_t stream) {
    const float* Q  = (const float*)d_in[0];
    const float* K  = (const float*)d_in[1];
    const float* V  = (const float*)d_in[2];
    const int* idx  = (const int*)d_in[3];
    float* out = (float*)d_out;

    float* M    = (float*)((char*)d_ws + OFF_M);
    int*   top  = (int*)  ((char*)d_ws + OFF_TOP);
    float* T    = (float*)((char*)d_ws + OFF_T);
    float* part = (float*)((char*)d_ws + OFF_PART);

    // K1: B*H*L waves, 4 waves/block
    k_msamp<<<(B * H * L) / 4, 256, 0, stream>>>(Q, K, idx, M);
    // K2: one wave per (b,h)
    k_topk<<<B * H, 64, 0, stream>>>(M, top);
    // K3a: 32 bh x 8 k-chunks
    k_scores<<<B * H * 8, 256, 0, stream>>>(Q, K, top, T);
    // K3b: one block per (bh,u) row
    k_softsuf<<<B * H * U, 256, 0, stream>>>(T);
    // K3c: 32 bh x 8 j-chunks
    k_ctx<<<B * H * 8, 256, 0, stream>>>(V, T, part);
    // reduce
    k_red<<<(B * H * U * D + 255) / 256, 256, 0, stream>>>(part, out);
}

// Round 2
// 318.930 us; speedup vs baseline: 1.2638x; 1.2638x over previous
//
#include <hip/hip_runtime.h>
#include <hip/hip_bf16.h>
#include <math.h>

#define B 4
#define L 2048
#define H 8
#define D 64
#define SK 40
#define U 40

// ws layout (bytes)
#define OFF_M    0           // B*H*L floats = 262144 B
#define OFF_TOP  262144      // B*H*U ints  = 5120 B
#define OFF_T    270336      // B*H*U*L floats = 10485760 B
#define OFF_PART 10756096    // 8 * B*H*U*D floats = 2621440 B

__device__ __forceinline__ float dot4(float4 a, float4 b) {
    return fmaf(a.x, b.x, fmaf(a.y, b.y, fmaf(a.z, b.z, a.w * b.w)));
}

// K1: M[b,h,q] = max_s dot(Q[bhq], K[bh,idx[q,s]]) - (1/L) * sum_s dot(...)
// One block per query q. thread t: bh = t>>3, d-chunk c = t&7.
// For each sample, the block reads K[b, ksel, :, :] for all b — contiguous
// 2 KB per b → fully coalesced (8 cache lines per load instr, not 64).
__global__ __launch_bounds__(256) void k_msamp(const float* __restrict__ Q,
                                               const float* __restrict__ K,
                                               const int* __restrict__ idx,
                                               float* __restrict__ M) {
    int q = blockIdx.x;
    int t = threadIdx.x;
    int bh = t >> 3;          // 0..31
    int c  = t & 7;           // d-chunk (8 floats each)
    int b = bh >> 3, h = bh & (H - 1);

    const float4* qp = (const float4*)(Q + (size_t)((b * L + q) * H + h) * D + c * 8);
    float4 q0 = qp[0], q1 = qp[1];

    const int* ip = idx + q * SK;                       // block-uniform -> s_load
    const float* kbase = K + (size_t)b * L * H * D + (size_t)h * D + c * 8;

    float vmax = -__builtin_inff();
    float vsum = 0.f;
#pragma unroll 4
    for (int s = 0; s < SK; ++s) {
        int kidx = ip[s];                               // uniform
        const float4* kp = (const float4*)(kbase + (size_t)kidx * (H * D));
        float4 k0 = kp[0], k1 = kp[1];
        float d8 = dot4(q0, k0) + dot4(q1, k1);
        // reduce across the 8 lanes of this bh group (c = low 3 bits of t)
        d8 += __shfl_xor(d8, 1, 64);
        d8 += __shfl_xor(d8, 2, 64);
        d8 += __shfl_xor(d8, 4, 64);
        vmax = fmaxf(vmax, d8);
        vsum += d8;
    }
    if (c == 0) M[(bh << 11) | q] = vmax - vsum * (1.0f / (float)L);
}

// K2: top-U argmax per (b,h), descending, ties -> lowest index (matches lax.top_k)
__global__ __launch_bounds__(256) void k_topk(const float* __restrict__ M,
                                              int* __restrict__ top) {
    __shared__ float v[L];
    __shared__ float wbest[4];
    __shared__ int   wbi[4];
    int bh = blockIdx.x;
    int tid = threadIdx.x;
    const float* m = M + (size_t)bh * L;
    for (int i = tid; i < L; i += 256) v[i] = m[i];
    __syncthreads();
    for (int it = 0; it < U; ++it) {
        float best = -__builtin_inff();
        int bi = 0x7fffffff;
        for (int i = tid; i < L; i += 256) {
            float val = v[i];
            if (val > best) { best = val; bi = i; }   // ascending i: lowest idx wins ties
        }
#pragma unroll
        for (int o = 32; o; o >>= 1) {
            float ob = __shfl_xor(best, o, 64);
            int   oi = __shfl_xor(bi, o, 64);
            if (ob > best || (ob == best && oi < bi)) { best = ob; bi = oi; }
        }
        if ((tid & 63) == 0) { wbest[tid >> 6] = best; wbi[tid >> 6] = bi; }
        __syncthreads();
        if (tid == 0) {
            float fb = wbest[0]; int fi = wbi[0];
#pragma unroll
            for (int w = 1; w < 4; ++w) {
                if (wbest[w] > fb || (wbest[w] == fb && wbi[w] < fi)) { fb = wbest[w]; fi = wbi[w]; }
            }
            top[bh * U + it] = fi;
            v[fi] = -__builtin_inff();
        }
        __syncthreads();
    }
}

// K3a: scores[bh,u,k] = 0.125 * dot(Q[bh, top[bh,u]], K[bh,k])
// thread-per-k, K row in registers, uniform Q loads
__global__ __launch_bounds__(256) void k_scores(const float* __restrict__ Q,
                                                const float* __restrict__ K,
                                                const int* __restrict__ top,
                                                float* __restrict__ T) {
    int bh = blockIdx.x >> 3;
    int kc = blockIdx.x & 7;
    int h = bh & (H - 1), b = bh >> 3;
    int k = kc * 256 + threadIdx.x;

    const float4* krow = (const float4*)(K + (size_t)((b * L + k) * H + h) * D);
    float4 kv[16];
#pragma unroll
    for (int i = 0; i < 16; ++i) kv[i] = krow[i];

    float* Trow = T + (size_t)bh * U * L + k;
    for (int u = 0; u < U; ++u) {
        int qidx = top[bh * U + u];  // uniform
        const float4* qrow = (const float4*)(Q + (size_t)((b * L + qidx) * H + h) * D);
        float s = 0.f;
#pragma unroll
        for (int i = 0; i < 16; ++i) s += dot4(qrow[i], kv[i]);
        Trow[(size_t)u * L] = s * 0.125f;
    }
}

// K3b: per row (bh,u): softmax over k then suffix-sum -> T[u,j] = sum_{k>=j} attn[k]
__global__ __launch_bounds__(256) void k_softsuf(float* __restrict__ T) {
    __shared__ float red[256];
    __shared__ float arr[256];
    int row = blockIdx.x;                  // [0, B*H*U)
    float* t = T + (size_t)row * L;
    int tid = threadIdx.x;

    const float4* p = (const float4*)(t + tid * 8);
    float4 a = p[0], c = p[1];
    float x[8] = {a.x, a.y, a.z, a.w, c.x, c.y, c.z, c.w};

    float mx = x[0];
#pragma unroll
    for (int i = 1; i < 8; ++i) mx = fmaxf(mx, x[i]);
    red[tid] = mx;
    __syncthreads();
    for (int s = 128; s; s >>= 1) {
        if (tid < s) red[tid] = fmaxf(red[tid], red[tid + s]);
        __syncthreads();
    }
    float maxv = red[0];
    __syncthreads();

    float e[8];
#pragma unroll
    for (int i = 0; i < 8; ++i) e[i] = __expf(x[i] - maxv);
    // local suffix sums
    float ls[8];
    ls[7] = e[7];
#pragma unroll
    for (int i = 6; i >= 0; --i) ls[i] = e[i] + ls[i + 1];
    float mytotal = ls[0];

    arr[tid] = mytotal;
    __syncthreads();
    for (int s = 1; s < 256; s <<= 1) {
        float add = (tid + s < 256) ? arr[tid + s] : 0.f;
        __syncthreads();
        arr[tid] += add;
        __syncthreads();
    }
    float denom = arr[0];
    float off = arr[tid] - mytotal;
    float r = 1.0f / denom;

    float4 o0 = make_float4((ls[0] + off) * r, (ls[1] + off) * r,
                            (ls[2] + off) * r, (ls[3] + off) * r);
    float4 o1 = make_float4((ls[4] + off) * r, (ls[5] + off) * r,
                            (ls[6] + off) * r, (ls[7] + off) * r);
    float4* po = (float4*)(t + tid * 8);
    po[0] = o0; po[1] = o1;
}

// K3c: partial context: part[jc,bh,u,d] = sum_{j in chunk} T[bh,u,j] * V[b,j,h,d]
__global__ __launch_bounds__(256) void k_ctx(const float* __restrict__ V,
                                             const float* __restrict__ T,
                                             float* __restrict__ part) {
    __shared__ float red[4 * U * D];   // 40 KiB
    int bh = blockIdx.x >> 3;
    int jc = blockIdx.x & 7;
    int b = bh >> 3, h = bh & (H - 1);
    int d  = threadIdx.x & 63;
    int jg = threadIdx.x >> 6;         // 0..3, wave id

    float acc[U];
#pragma unroll
    for (int u = 0; u < U; ++u) acc[u] = 0.f;

    const float* Tb = T + (size_t)bh * U * L;
    for (int jj4 = 0; jj4 < 16; ++jj4) {
        int j0 = jc * 256 + jg * 64 + jj4 * 4;
        float v0 = V[(size_t)((b * L + j0 + 0) * H + h) * D + d];
        float v1 = V[(size_t)((b * L + j0 + 1) * H + h) * D + d];
        float v2 = V[(size_t)((b * L + j0 + 2) * H + h) * D + d];
        float v3 = V[(size_t)((b * L + j0 + 3) * H + h) * D + d];
#pragma unroll
        for (int u = 0; u < U; ++u) {
            float4 tv = *(const float4*)(Tb + (size_t)u * L + j0);  // wave-uniform
            acc[u] = fmaf(tv.x, v0, fmaf(tv.y, v1, fmaf(tv.z, v2, fmaf(tv.w, v3, acc[u]))));
        }
    }

#pragma unroll
    for (int u = 0; u < U; ++u) red[(jg * U + u) * D + d] = acc[u];
    __syncthreads();
    for (int i = threadIdx.x; i < U * D; i += 256) {
        float s = red[i] + red[U * D + i] + red[2 * U * D + i] + red[3 * U * D + i];
        part[(size_t)(jc * (B * H) + bh) * (U * D) + i] = s;
    }
}

// final reduce over the 8 j-chunks
__global__ __launch_bounds__(256) void k_red(const float* __restrict__ part,
                                             float* __restrict__ out) {
    int o = blockIdx.x * 256 + threadIdx.x;
    if (o >= B * H * U * D) return;
    int bh = o / (U * D);
    int rest = o - bh * (U * D);
    float s = 0.f;
#pragma unroll
    for (int jc = 0; jc < 8; ++jc)
        s += part[(size_t)(jc * (B * H) + bh) * (U * D) + rest];
    out[o] = s;
}

extern "C" void kernel_launch(void* const* d_in, const int* in_sizes, int n_in,
                              void* d_out, int out_size, void* d_ws, size_t ws_size,
                              hipStream_t stream) {
    const float* Q  = (const float*)d_in[0];
    const float* K  = (const float*)d_in[1];
    const float* V  = (const float*)d_in[2];
    const int* idx  = (const int*)d_in[3];
    float* out = (float*)d_out;

    float* M    = (float*)((char*)d_ws + OFF_M);
    int*   top  = (int*)  ((char*)d_ws + OFF_TOP);
    float* T    = (float*)((char*)d_ws + OFF_T);
    float* part = (float*)((char*)d_ws + OFF_PART);

    // K1: one block per query
    k_msamp<<<L, 256, 0, stream>>>(Q, K, idx, M);
    // K2: one block per (b,h)
    k_topk<<<B * H, 256, 0, stream>>>(M, top);
    // K3a: 32 bh x 8 k-chunks
    k_scores<<<B * H * 8, 256, 0, stream>>>(Q, K, top, T);
    // K3b: one block per (bh,u) row
    k_softsuf<<<B * H * U, 256, 0, stream>>>(T);
    // K3c: 32 bh x 8 j-chunks
    k_ctx<<<B * H * 8, 256, 0, stream>>>(V, T, part);
    // reduce
    k_red<<<(B * H * U * D + 255) / 256, 256, 0, stream>>>(part, out);
}

// Round 3
// 243.688 us; speedup vs baseline: 1.6540x; 1.3088x over previous
//
#include <hip/hip_runtime.h>
#include <hip/hip_bf16.h>
#include <math.h>

#define B 4
#define L 2048
#define H 8
#define D 64
#define SK 40
#define U 40
#define JC 32          // j-chunks in k_ctx
#define JCL (L / JC)   // 64 j per chunk

// ws layout (bytes)
#define OFF_M    0                  // B*H*L floats = 262144 B
#define OFF_TOP  262144             // B*H*U ints  = 5120 B
#define OFF_T    270336             // B*H*U*L floats = 10485760 B
#define OFF_PART 10756096           // JC * B*H*U*D floats = 10485760 B  (end ~21.2 MB)

__device__ __forceinline__ float dot4(float4 a, float4 b) {
    return fmaf(a.x, b.x, fmaf(a.y, b.y, fmaf(a.z, b.z, a.w * b.w)));
}

// K1: M[b,h,q] = max_s dot(Q[bhq], K[bh,idx[q,s]]) - (1/L) * sum_s dot(...)
// One block per query q. thread t: bh = t>>3, d-chunk c = t&7.
__global__ __launch_bounds__(256) void k_msamp(const float* __restrict__ Q,
                                               const float* __restrict__ K,
                                               const int* __restrict__ idx,
                                               float* __restrict__ M) {
    int q = blockIdx.x;
    int t = threadIdx.x;
    int bh = t >> 3;          // 0..31
    int c  = t & 7;           // d-chunk (8 floats each)
    int b = bh >> 3, h = bh & (H - 1);

    const float4* qp = (const float4*)(Q + (size_t)((b * L + q) * H + h) * D + c * 8);
    float4 q0 = qp[0], q1 = qp[1];

    const int* ip = idx + q * SK;                       // block-uniform -> s_load
    const float* kbase = K + (size_t)b * L * H * D + (size_t)h * D + c * 8;

    float vmax = -__builtin_inff();
    float vsum = 0.f;
#pragma unroll 4
    for (int s = 0; s < SK; ++s) {
        int kidx = ip[s];                               // uniform
        const float4* kp = (const float4*)(kbase + (size_t)kidx * (H * D));
        float4 k0 = kp[0], k1 = kp[1];
        float d8 = dot4(q0, k0) + dot4(q1, k1);
        d8 += __shfl_xor(d8, 1, 64);
        d8 += __shfl_xor(d8, 2, 64);
        d8 += __shfl_xor(d8, 4, 64);
        vmax = fmaxf(vmax, d8);
        vsum += d8;
    }
    if (c == 0) M[(bh << 11) | q] = vmax - vsum * (1.0f / (float)L);
}

// K2: top-U argmax per (b,h), ties -> lowest index (matches lax.top_k)
__global__ __launch_bounds__(256) void k_topk(const float* __restrict__ M,
                                              int* __restrict__ top) {
    __shared__ float v[L];
    __shared__ float wbest[4];
    __shared__ int   wbi[4];
    int bh = blockIdx.x;
    int tid = threadIdx.x;
    const float* m = M + (size_t)bh * L;
    for (int i = tid; i < L; i += 256) v[i] = m[i];
    __syncthreads();
    for (int it = 0; it < U; ++it) {
        float best = -__builtin_inff();
        int bi = 0x7fffffff;
        for (int i = tid; i < L; i += 256) {
            float val = v[i];
            if (val > best) { best = val; bi = i; }
        }
#pragma unroll
        for (int o = 32; o; o >>= 1) {
            float ob = __shfl_xor(best, o, 64);
            int   oi = __shfl_xor(bi, o, 64);
            if (ob > best || (ob == best && oi < bi)) { best = ob; bi = oi; }
        }
        if ((tid & 63) == 0) { wbest[tid >> 6] = best; wbi[tid >> 6] = bi; }
        __syncthreads();
        if (tid == 0) {
            float fb = wbest[0]; int fi = wbi[0];
#pragma unroll
            for (int w = 1; w < 4; ++w) {
                if (wbest[w] > fb || (wbest[w] == fb && wbi[w] < fi)) { fb = wbest[w]; fi = wbi[w]; }
            }
            top[bh * U + it] = fi;
            v[fi] = -__builtin_inff();
        }
        __syncthreads();
    }
}

// K3a: T[bh,u,k] = 0.125 * dot(Q[bh, top[bh,u]], K[bh,k])
// Q_sel staged in LDS (broadcast ds_read_b128), 2 K rows per thread in regs,
// wave w handles u in [10w, 10w+10).
__global__ __launch_bounds__(256) void k_scores(const float* __restrict__ Q,
                                                const float* __restrict__ K,
                                                const int* __restrict__ top,
                                                float* __restrict__ T) {
    __shared__ float4 sQ4[U * 16];   // 40 rows x 64 floats = 10 KB
    int bh = blockIdx.x >> 4;        // 16 k-chunks
    int kc = blockIdx.x & 15;
    int b = bh >> 3, h = bh & (H - 1);
    int tid = threadIdx.x;
    int lane = tid & 63;
    int w = tid >> 6;

    for (int i = tid; i < U * 16; i += 256) {
        int u = i >> 4, c = i & 15;
        int qidx = top[bh * U + u];
        sQ4[i] = *((const float4*)(Q + (size_t)((b * L + qidx) * H + h) * D) + c);
    }

    int k0 = kc * 128 + lane;
    const float4* kr0 = (const float4*)(K + (size_t)((b * L + k0) * H + h) * D);
    const float4* kr1 = (const float4*)(K + (size_t)((b * L + k0 + 64) * H + h) * D);
    float4 kv0[16], kv1[16];
#pragma unroll
    for (int i = 0; i < 16; ++i) { kv0[i] = kr0[i]; kv1[i] = kr1[i]; }
    __syncthreads();

    float* Tb = T + (size_t)bh * U * L;
    for (int uu = 0; uu < 10; ++uu) {
        int u = w * 10 + uu;
        float s0 = 0.f, s1 = 0.f;
#pragma unroll
        for (int i = 0; i < 16; ++i) {
            float4 q4 = sQ4[u * 16 + i];   // broadcast LDS read
            s0 += dot4(q4, kv0[i]);
            s1 += dot4(q4, kv1[i]);
        }
        Tb[(size_t)u * L + k0]      = s0 * 0.125f;
        Tb[(size_t)u * L + k0 + 64] = s1 * 0.125f;
    }
}

// K3b: per row (bh,u): softmax over k then suffix-sum -> T[u,j] = sum_{k>=j} attn[k]
__global__ __launch_bounds__(256) void k_softsuf(float* __restrict__ T) {
    __shared__ float red[256];
    __shared__ float arr[256];
    int row = blockIdx.x;                  // [0, B*H*U)
    float* t = T + (size_t)row * L;
    int tid = threadIdx.x;

    const float4* p = (const float4*)(t + tid * 8);
    float4 a = p[0], c = p[1];
    float x[8] = {a.x, a.y, a.z, a.w, c.x, c.y, c.z, c.w};

    float mx = x[0];
#pragma unroll
    for (int i = 1; i < 8; ++i) mx = fmaxf(mx, x[i]);
    red[tid] = mx;
    __syncthreads();
    for (int s = 128; s; s >>= 1) {
        if (tid < s) red[tid] = fmaxf(red[tid], red[tid + s]);
        __syncthreads();
    }
    float maxv = red[0];
    __syncthreads();

    float e[8];
#pragma unroll
    for (int i = 0; i < 8; ++i) e[i] = __expf(x[i] - maxv);
    float ls[8];
    ls[7] = e[7];
#pragma unroll
    for (int i = 6; i >= 0; --i) ls[i] = e[i] + ls[i + 1];
    float mytotal = ls[0];

    arr[tid] = mytotal;
    __syncthreads();
    for (int s = 1; s < 256; s <<= 1) {
        float add = (tid + s < 256) ? arr[tid + s] : 0.f;
        __syncthreads();
        arr[tid] += add;
        __syncthreads();
    }
    float denom = arr[0];
    float off = arr[tid] - mytotal;
    float r = 1.0f / denom;

    float4 o0 = make_float4((ls[0] + off) * r, (ls[1] + off) * r,
                            (ls[2] + off) * r, (ls[3] + off) * r);
    float4 o1 = make_float4((ls[4] + off) * r, (ls[5] + off) * r,
                            (ls[6] + off) * r, (ls[7] + off) * r);
    float4* po = (float4*)(t + tid * 8);
    po[0] = o0; po[1] = o1;
}

// K3c: part[jc,bh,u,d] = sum_{j in chunk jc} T[bh,u,j] * V[b,j,h,d]
// T tile staged in LDS; lane = d; wave w owns u in [10w,10w+10) -> no
// cross-wave reduction needed.
__global__ __launch_bounds__(256) void k_ctx(const float* __restrict__ V,
                                             const float* __restrict__ T,
                                             float* __restrict__ part) {
    __shared__ float4 sT4[U * (JCL / 4)];   // 40 x 16 float4 = 10 KB
    int bh = blockIdx.x >> 5;               // JC = 32 chunks
    int jc = blockIdx.x & 31;
    int b = bh >> 3, h = bh & (H - 1);
    int tid = threadIdx.x;
    int d = tid & 63;
    int w = tid >> 6;

    const float4* Tg = (const float4*)(T + (size_t)bh * U * L);
    for (int i = tid; i < U * (JCL / 4); i += 256) {
        int u = i >> 4;          // JCL/4 = 16
        int c = i & 15;
        sT4[i] = Tg[u * (L / 4) + jc * (JCL / 4) + c];
    }
    __syncthreads();

    float acc[10];
#pragma unroll
    for (int uu = 0; uu < 10; ++uu) acc[uu] = 0.f;

    const float* Vb = V + (size_t)b * L * H * D + (size_t)h * D + d;
#pragma unroll 2
    for (int jj = 0; jj < JCL / 4; ++jj) {
        int j0 = jc * JCL + jj * 4;
        float v0 = Vb[(size_t)(j0 + 0) * (H * D)];
        float v1 = Vb[(size_t)(j0 + 1) * (H * D)];
        float v2 = Vb[(size_t)(j0 + 2) * (H * D)];
        float v3 = Vb[(size_t)(j0 + 3) * (H * D)];
#pragma unroll
        for (int uu = 0; uu < 10; ++uu) {
            float4 t4 = sT4[(w * 10 + uu) * 16 + jj];   // broadcast LDS read
            acc[uu] = fmaf(t4.x, v0, fmaf(t4.y, v1, fmaf(t4.z, v2, fmaf(t4.w, v3, acc[uu]))));
        }
    }

    float* po = part + ((size_t)jc * (B * H) + bh) * (U * D);
#pragma unroll
    for (int uu = 0; uu < 10; ++uu) po[(w * 10 + uu) * D + d] = acc[uu];
}

// final reduce over the JC j-chunks
__global__ __launch_bounds__(256) void k_red(const float* __restrict__ part,
                                             float* __restrict__ out) {
    int o = blockIdx.x * 256 + threadIdx.x;
    if (o >= B * H * U * D) return;
    int bh = o / (U * D);
    int rest = o - bh * (U * D);
    float s = 0.f;
#pragma unroll
    for (int jc = 0; jc < JC; ++jc)
        s += part[(size_t)(jc * (B * H) + bh) * (U * D) + rest];
    out[o] = s;
}

extern "C" void kernel_launch(void* const* d_in, const int* in_sizes, int n_in,
                              void* d_out, int out_size, void* d_ws, size_t ws_size,
                              hipStream_t stream) {
    const float* Q  = (const float*)d_in[0];
    const float* K  = (const float*)d_in[1];
    const float* V  = (const float*)d_in[2];
    const int* idx  = (const int*)d_in[3];
    float* out = (float*)d_out;

    float* M    = (float*)((char*)d_ws + OFF_M);
    int*   top  = (int*)  ((char*)d_ws + OFF_TOP);
    float* T    = (float*)((char*)d_ws + OFF_T);
    float* part = (float*)((char*)d_ws + OFF_PART);

    k_msamp<<<L, 256, 0, stream>>>(Q, K, idx, M);
    k_topk<<<B * H, 256, 0, stream>>>(M, top);
    k_scores<<<B * H * 16, 256, 0, stream>>>(Q, K, top, T);
    k_softsuf<<<B * H * U, 256, 0, stream>>>(T);
    k_ctx<<<B * H * JC, 256, 0, stream>>>(V, T, part);
    k_red<<<(B * H * U * D + 255) / 256, 256, 0, stream>>>(part, out);
}

// Round 4
// 201.166 us; speedup vs baseline: 2.0036x; 1.2114x over previous
//
#include <hip/hip_runtime.h>
#include <hip/hip_bf16.h>
#include <math.h>

#define B 4
#define L 2048
#define H 8
#define D 64
#define SK 40
#define U 40
#define JC 32          // j-chunks in k_ctx
#define JCL (L / JC)   // 64 j per chunk

// ws layout (bytes)
#define OFF_M    0                  // B*H*L floats = 262144 B
#define OFF_TOP  262144             // B*H*U ints  = 5120 B
#define OFF_T    270336             // B*H*U*L floats = 10485760 B
#define OFF_PART 10756096           // JC * B*H*U*D floats = 10485760 B  (end ~21.2 MB)

__device__ __forceinline__ float dot4(float4 a, float4 b) {
    return fmaf(a.x, b.x, fmaf(a.y, b.y, fmaf(a.z, b.z, a.w * b.w)));
}

// K1: M[b,h,q] = max_s dot(Q[bhq], K[bh,idx[q,s]]) - (1/L) * sum_s dot(...)
// XCD-locality version: blockIdx%8 == b*2+hh pins each (b, h-half) to one XCD
// whose K working set is L*4*D*4B = 2.1 MB < 4 MB L2 -> gathers hit local L2.
// Block = 4 waves; wave = one q; lane = (h' in 0..3) x (c in 0..15).
// Per sample the wave reads K[b, kidx, hh*4..hh*4+4, :] = 1 KB contiguous.
__global__ __launch_bounds__(256) void k_msamp(const float* __restrict__ Q,
                                               const float* __restrict__ K,
                                               const int* __restrict__ idx,
                                               float* __restrict__ M) {
    int g  = blockIdx.x & 7;        // = b*2 + hh  (XCD id under %8 round-robin)
    int b  = g >> 1;
    int hh = g & 1;
    int t  = threadIdx.x;
    int q  = (blockIdx.x >> 3) * 4 + (t >> 6);
    int c  = t & 15;                // 16 c-chunks of 4 floats
    int hp = (t >> 4) & 3;          // h' within half
    int h  = hh * 4 + hp;

    float4 q4 = *((const float4*)(Q + (size_t)((b * L + q) * H + h) * D) + c);

    const int* ip = idx + q * SK;   // wave-uniform
    const float* kbase = K + (size_t)b * L * H * D + (size_t)h * D + c * 4;

    float vmax = -__builtin_inff();
    float vsum = 0.f;
#pragma unroll 8
    for (int s = 0; s < SK; ++s) {
        int kidx = ip[s];           // wave-uniform
        float4 k4 = *(const float4*)(kbase + (size_t)kidx * (H * D));
        float d4 = dot4(q4, k4);
        // reduce across the 16 c-lanes of this h group
        d4 += __shfl_xor(d4, 1, 64);
        d4 += __shfl_xor(d4, 2, 64);
        d4 += __shfl_xor(d4, 4, 64);
        d4 += __shfl_xor(d4, 8, 64);
        vmax = fmaxf(vmax, d4);
        vsum += d4;
    }
    if (c == 0) M[(size_t)(b * H + h) * L + q] = vmax - vsum * (1.0f / (float)L);
}

// K2: top-U argmax per (b,h), ties -> lowest index (matches lax.top_k)
__global__ __launch_bounds__(256) void k_topk(const float* __restrict__ M,
                                              int* __restrict__ top) {
    __shared__ float v[L];
    __shared__ float wbest[4];
    __shared__ int   wbi[4];
    int bh = blockIdx.x;
    int tid = threadIdx.x;
    const float* m = M + (size_t)bh * L;
    for (int i = tid; i < L; i += 256) v[i] = m[i];
    __syncthreads();
    for (int it = 0; it < U; ++it) {
        float best = -__builtin_inff();
        int bi = 0x7fffffff;
        for (int i = tid; i < L; i += 256) {
            float val = v[i];
            if (val > best) { best = val; bi = i; }
        }
#pragma unroll
        for (int o = 32; o; o >>= 1) {
            float ob = __shfl_xor(best, o, 64);
            int   oi = __shfl_xor(bi, o, 64);
            if (ob > best || (ob == best && oi < bi)) { best = ob; bi = oi; }
        }
        if ((tid & 63) == 0) { wbest[tid >> 6] = best; wbi[tid >> 6] = bi; }
        __syncthreads();
        if (tid == 0) {
            float fb = wbest[0]; int fi = wbi[0];
#pragma unroll
            for (int w = 1; w < 4; ++w) {
                if (wbest[w] > fb || (wbest[w] == fb && wbi[w] < fi)) { fb = wbest[w]; fi = wbi[w]; }
            }
            top[bh * U + it] = fi;
            v[fi] = -__builtin_inff();
        }
        __syncthreads();
    }
}

// K3a: T[bh,u,k] = 0.125 * dot(Q[bh, top[bh,u]], K[bh,k])
__global__ __launch_bounds__(256) void k_scores(const float* __restrict__ Q,
                                                const float* __restrict__ K,
                                                const int* __restrict__ top,
                                                float* __restrict__ T) {
    __shared__ float4 sQ4[U * 16];   // 40 rows x 64 floats = 10 KB
    int bh = blockIdx.x >> 4;        // 16 k-chunks
    int kc = blockIdx.x & 15;
    int b = bh >> 3, h = bh & (H - 1);
    int tid = threadIdx.x;
    int lane = tid & 63;
    int w = tid >> 6;

    for (int i = tid; i < U * 16; i += 256) {
        int u = i >> 4, c = i & 15;
        int qidx = top[bh * U + u];
        sQ4[i] = *((const float4*)(Q + (size_t)((b * L + qidx) * H + h) * D) + c);
    }

    int k0 = kc * 128 + lane;
    const float4* kr0 = (const float4*)(K + (size_t)((b * L + k0) * H + h) * D);
    const float4* kr1 = (const float4*)(K + (size_t)((b * L + k0 + 64) * H + h) * D);
    float4 kv0[16], kv1[16];
#pragma unroll
    for (int i = 0; i < 16; ++i) { kv0[i] = kr0[i]; kv1[i] = kr1[i]; }
    __syncthreads();

    float* Tb = T + (size_t)bh * U * L;
    for (int uu = 0; uu < 10; ++uu) {
        int u = w * 10 + uu;
        float s0 = 0.f, s1 = 0.f;
#pragma unroll
        for (int i = 0; i < 16; ++i) {
            float4 q4 = sQ4[u * 16 + i];   // broadcast LDS read
            s0 += dot4(q4, kv0[i]);
            s1 += dot4(q4, kv1[i]);
        }
        Tb[(size_t)u * L + k0]      = s0 * 0.125f;
        Tb[(size_t)u * L + k0 + 64] = s1 * 0.125f;
    }
}

// K3b: per row (bh,u): softmax over k then suffix-sum -> T[u,j] = sum_{k>=j} attn[k]
__global__ __launch_bounds__(256) void k_softsuf(float* __restrict__ T) {
    __shared__ float red[256];
    __shared__ float arr[256];
    int row = blockIdx.x;                  // [0, B*H*U)
    float* t = T + (size_t)row * L;
    int tid = threadIdx.x;

    const float4* p = (const float4*)(t + tid * 8);
    float4 a = p[0], c = p[1];
    float x[8] = {a.x, a.y, a.z, a.w, c.x, c.y, c.z, c.w};

    float mx = x[0];
#pragma unroll
    for (int i = 1; i < 8; ++i) mx = fmaxf(mx, x[i]);
    red[tid] = mx;
    __syncthreads();
    for (int s = 128; s; s >>= 1) {
        if (tid < s) red[tid] = fmaxf(red[tid], red[tid + s]);
        __syncthreads();
    }
    float maxv = red[0];
    __syncthreads();

    float e[8];
#pragma unroll
    for (int i = 0; i < 8; ++i) e[i] = __expf(x[i] - maxv);
    float ls[8];
    ls[7] = e[7];
#pragma unroll
    for (int i = 6; i >= 0; --i) ls[i] = e[i] + ls[i + 1];
    float mytotal = ls[0];

    arr[tid] = mytotal;
    __syncthreads();
    for (int s = 1; s < 256; s <<= 1) {
        float add = (tid + s < 256) ? arr[tid + s] : 0.f;
        __syncthreads();
        arr[tid] += add;
        __syncthreads();
    }
    float denom = arr[0];
    float off = arr[tid] - mytotal;
    float r = 1.0f / denom;

    float4 o0 = make_float4((ls[0] + off) * r, (ls[1] + off) * r,
                            (ls[2] + off) * r, (ls[3] + off) * r);
    float4 o1 = make_float4((ls[4] + off) * r, (ls[5] + off) * r,
                            (ls[6] + off) * r, (ls[7] + off) * r);
    float4* po = (float4*)(t + tid * 8);
    po[0] = o0; po[1] = o1;
}

// K3c: part[jc,bh,u,d] = sum_{j in chunk jc} T[bh,u,j] * V[b,j,h,d]
__global__ __launch_bounds__(256) void k_ctx(const float* __restrict__ V,
                                             const float* __restrict__ T,
                                             float* __restrict__ part) {
    __shared__ float4 sT4[U * (JCL / 4)];   // 40 x 16 float4 = 10 KB
    int bh = blockIdx.x >> 5;               // JC = 32 chunks
    int jc = blockIdx.x & 31;
    int b = bh >> 3, h = bh & (H - 1);
    int tid = threadIdx.x;
    int d = tid & 63;
    int w = tid >> 6;

    const float4* Tg = (const float4*)(T + (size_t)bh * U * L);
    for (int i = tid; i < U * (JCL / 4); i += 256) {
        int u = i >> 4;          // JCL/4 = 16
        int c = i & 15;
        sT4[i] = Tg[u * (L / 4) + jc * (JCL / 4) + c];
    }
    __syncthreads();

    float acc[10];
#pragma unroll
    for (int uu = 0; uu < 10; ++uu) acc[uu] = 0.f;

    const float* Vb = V + (size_t)b * L * H * D + (size_t)h * D + d;
#pragma unroll 2
    for (int jj = 0; jj < JCL / 4; ++jj) {
        int j0 = jc * JCL + jj * 4;
        float v0 = Vb[(size_t)(j0 + 0) * (H * D)];
        float v1 = Vb[(size_t)(j0 + 1) * (H * D)];
        float v2 = Vb[(size_t)(j0 + 2) * (H * D)];
        float v3 = Vb[(size_t)(j0 + 3) * (H * D)];
#pragma unroll
        for (int uu = 0; uu < 10; ++uu) {
            float4 t4 = sT4[(w * 10 + uu) * 16 + jj];   // broadcast LDS read
            acc[uu] = fmaf(t4.x, v0, fmaf(t4.y, v1, fmaf(t4.z, v2, fmaf(t4.w, v3, acc[uu]))));
        }
    }

    float* po = part + ((size_t)jc * (B * H) + bh) * (U * D);
#pragma unroll
    for (int uu = 0; uu < 10; ++uu) po[(w * 10 + uu) * D + d] = acc[uu];
}

// final reduce over the JC j-chunks
__global__ __launch_bounds__(256) void k_red(const float* __restrict__ part,
                                             float* __restrict__ out) {
    int o = blockIdx.x * 256 + threadIdx.x;
    if (o >= B * H * U * D) return;
    int bh = o / (U * D);
    int rest = o - bh * (U * D);
    float s = 0.f;
#pragma unroll
    for (int jc = 0; jc < JC; ++jc)
        s += part[(size_t)(jc * (B * H) + bh) * (U * D) + rest];
    out[o] = s;
}

extern "C" void kernel_launch(void* const* d_in, const int* in_sizes, int n_in,
                              void* d_out, int out_size, void* d_ws, size_t ws_size,
                              hipStream_t stream) {
    const float* Q  = (const float*)d_in[0];
    const float* K  = (const float*)d_in[1];
    const float* V  = (const float*)d_in[2];
    const int* idx  = (const int*)d_in[3];
    float* out = (float*)d_out;

    float* M    = (float*)((char*)d_ws + OFF_M);
    int*   top  = (int*)  ((char*)d_ws + OFF_TOP);
    float* T    = (float*)((char*)d_ws + OFF_T);
    float* part = (float*)((char*)d_ws + OFF_PART);

    // K1: 512 q-quads x 8 (b,hh) groups; %8 pins (b,hh) to an XCD
    k_msamp<<<(L / 4) * 8, 256, 0, stream>>>(Q, K, idx, M);
    k_topk<<<B * H, 256, 0, stream>>>(M, top);
    k_scores<<<B * H * 16, 256, 0, stream>>>(Q, K, top, T);
    k_softsuf<<<B * H * U, 256, 0, stream>>>(T);
    k_ctx<<<B * H * JC, 256, 0, stream>>>(V, T, part);
    k_red<<<(B * H * U * D + 255) / 256, 256, 0, stream>>>(part, out);
}